// Round 1
// baseline (143.736 us; speedup 1.0000x reference)
//
#include <hip/hip_runtime.h>

// NNUE forward: sparse feature transform (gather+sum) -> crelu -> concat
// -> fc1(512x32) -> crelu -> fc2(32x32) -> crelu -> fc3(32x1)
//
// Layout facts from the reference:
//   white_indices/black_indices: [2, NNZ] int32, row 0 = batch idx
//     (= repeat(arange(16384), 32), so board b owns slice [b*32,(b+1)*32)),
//     row 1 = feature idx in [0, 40960).
//   values: all-ones f32 (multiplied anyway for fidelity).
//   ft_w: [40960, 256] f32 row-major; fc1_w: [512,32]; fc2_w: [32,32];
//   fc3_w: [32,1]. Output: [16384,1] f32.

constexpr int BATCH  = 16384;
constexpr int NNZPB  = 32;            // nnz per board
constexpr int NNZ    = BATCH * NNZPB; // 524288
constexpr int HIDDEN = 256;

__device__ __forceinline__ float crelu1(float v) {
    return fminf(fmaxf(v, 0.0f), 1.0f);
}

__global__ __launch_bounds__(256) void nnue_fwd(
    const int*    __restrict__ wfeat,  // white feature idx (row 1)
    const float*  __restrict__ wval,
    const int*    __restrict__ bfeat,  // black feature idx (row 1)
    const float*  __restrict__ bval,
    const float4* __restrict__ ftw,    // [40960][64] as float4
    const float4* __restrict__ ftb,    // [64] as float4
    const float*  __restrict__ fc1w,   // [512][32]
    const float*  __restrict__ fc1b,   // [32]
    const float*  __restrict__ fc2w,   // [32][32]
    const float*  __restrict__ fc2b,   // [32]
    const float*  __restrict__ fc3w,   // [32]
    const float*  __restrict__ fc3b,   // [1]
    float*        __restrict__ out)    // [16384]
{
    __shared__ float x[4][2 * HIDDEN];   // concat(w, b) per board
    __shared__ float p1[4][2][32];       // fc1 partial sums
    __shared__ float h1[4][32];
    __shared__ float h2[4][32];

    const int tid   = threadIdx.x;
    const int w     = tid >> 6;          // wave id = board slot in block
    const int lane  = tid & 63;
    const int board = (blockIdx.x << 2) + w;

    // ---- feature transform (white) : lane owns hidden units [4*lane,4*lane+4)
    {
        const int*   ip = wfeat + board * NNZPB;
        const float* vp = wval  + board * NNZPB;
        float4 acc = ftb[lane];
        #pragma unroll
        for (int k = 0; k < NNZPB; ++k) {
            const int   f = ip[k];
            const float v = vp[k];
            const float4 r = ftw[f * 64 + lane];
            acc.x = fmaf(r.x, v, acc.x);
            acc.y = fmaf(r.y, v, acc.y);
            acc.z = fmaf(r.z, v, acc.z);
            acc.w = fmaf(r.w, v, acc.w);
        }
        float4 c;
        c.x = crelu1(acc.x); c.y = crelu1(acc.y);
        c.z = crelu1(acc.z); c.w = crelu1(acc.w);
        reinterpret_cast<float4*>(x[w])[lane] = c;
    }

    // ---- feature transform (black)
    {
        const int*   ip = bfeat + board * NNZPB;
        const float* vp = bval  + board * NNZPB;
        float4 acc = ftb[lane];
        #pragma unroll
        for (int k = 0; k < NNZPB; ++k) {
            const int   f = ip[k];
            const float v = vp[k];
            const float4 r = ftw[f * 64 + lane];
            acc.x = fmaf(r.x, v, acc.x);
            acc.y = fmaf(r.y, v, acc.y);
            acc.z = fmaf(r.z, v, acc.z);
            acc.w = fmaf(r.w, v, acc.w);
        }
        float4 c;
        c.x = crelu1(acc.x); c.y = crelu1(acc.y);
        c.z = crelu1(acc.z); c.w = crelu1(acc.w);
        reinterpret_cast<float4*>(x[w])[64 + lane] = c;
    }

    __syncthreads();

    // ---- fc1: out[o] = sum_{i<512} x[i] * fc1w[i*32+o]
    // lane -> (o = lane&31, half = lane>>5); each lane does a 256-elem dot.
    {
        const int o = lane & 31;
        const int h = lane >> 5;
        const float* xr = &x[w][h * HIDDEN];
        const float* wr = fc1w + (h * HIDDEN) * 32 + o;
        float s = 0.0f;
        #pragma unroll 8
        for (int i = 0; i < HIDDEN; ++i)
            s = fmaf(xr[i], wr[i * 32], s);
        p1[w][h][o] = s;
    }
    __syncthreads();

    if (lane < 32) {
        const float v = p1[w][0][lane] + p1[w][1][lane] + fc1b[lane];
        h1[w][lane] = crelu1(v);
    }
    __syncthreads();

    // ---- fc2
    if (lane < 32) {
        float s = fc2b[lane];
        #pragma unroll
        for (int i = 0; i < 32; ++i)
            s = fmaf(h1[w][i], fc2w[i * 32 + lane], s);
        h2[w][lane] = crelu1(s);
    }
    __syncthreads();

    // ---- fc3 (32 -> 1)
    if (lane == 0) {
        float s = fc3b[0];
        #pragma unroll
        for (int i = 0; i < 32; ++i)
            s = fmaf(h2[w][i], fc3w[i], s);
        out[board] = s;
    }
}

extern "C" void kernel_launch(void* const* d_in, const int* in_sizes, int n_in,
                              void* d_out, int out_size, void* d_ws, size_t ws_size,
                              hipStream_t stream) {
    const int*   w_indices = (const int*)  d_in[0];   // [2, NNZ]
    const float* w_values  = (const float*)d_in[1];
    const int*   b_indices = (const int*)  d_in[2];
    const float* b_values  = (const float*)d_in[3];
    const float* ft_w      = (const float*)d_in[4];
    const float* ft_b      = (const float*)d_in[5];
    const float* fc1_w     = (const float*)d_in[6];
    const float* fc1_b     = (const float*)d_in[7];
    const float* fc2_w     = (const float*)d_in[8];
    const float* fc2_b     = (const float*)d_in[9];
    const float* fc3_w     = (const float*)d_in[10];
    const float* fc3_b     = (const float*)d_in[11];
    float* out = (float*)d_out;

    const int* wfeat = w_indices + NNZ;  // row 1 = feature indices
    const int* bfeat = b_indices + NNZ;

    dim3 grid(BATCH / 4);
    dim3 block(256);
    nnue_fwd<<<grid, block, 0, stream>>>(
        wfeat, w_values, bfeat, b_values,
        (const float4*)ft_w, (const float4*)ft_b,
        fc1_w, fc1_b, fc2_w, fc2_b, fc3_w, fc3_b, out);
}

// Round 2
// 100.423 us; speedup vs baseline: 1.4313x; 1.4313x over previous
//
#include <hip/hip_runtime.h>
#include <hip/hip_fp16.h>

// NNUE forward. R2: fp16-compressed feature table in d_ws (halves gather
// bytes; f32 accumulate everywhere), coalesced index loads + shfl broadcast,
// interleaved white/black gathers for 2x memory-level parallelism.

constexpr int BATCH   = 16384;
constexpr int NNZPB   = 32;
constexpr int NNZ     = BATCH * NNZPB;
constexpr int HIDDEN  = 256;
constexpr int FEATSZ  = 64 * 64 * 10;                       // 40960
constexpr size_t FTW16_BYTES = (size_t)FEATSZ * HIDDEN * 2; // 20,971,520

__device__ __forceinline__ float crelu1(float v) {
    return fminf(fmaxf(v, 0.0f), 1.0f);
}

// ---- one-pass f32 -> fp16 table conversion (runs every launch; ~10us) ----
__global__ __launch_bounds__(256) void convert_ftw(
    const float4* __restrict__ src,   // ft_w as float4, n4 elements
    uint2*        __restrict__ dst,   // 4 halfs per element
    int n4)
{
    int i = blockIdx.x * 256 + threadIdx.x;
    const int stride = gridDim.x * 256;
    for (; i < n4; i += stride) {
        const float4 v = src[i];
        const __half2 lo = __floats2half2_rn(v.x, v.y);
        const __half2 hi = __floats2half2_rn(v.z, v.w);
        uint2 o;
        o.x = *reinterpret_cast<const unsigned*>(&lo);
        o.y = *reinterpret_cast<const unsigned*>(&hi);
        dst[i] = o;
    }
}

__device__ __forceinline__ void fma4_fp16(const uint2 r, float v, float4& acc) {
    const __half2 h0 = *reinterpret_cast<const __half2*>(&r.x);
    const __half2 h1 = *reinterpret_cast<const __half2*>(&r.y);
    const float2 f0 = __half22float2(h0);
    const float2 f1 = __half22float2(h1);
    acc.x = fmaf(f0.x, v, acc.x);
    acc.y = fmaf(f0.y, v, acc.y);
    acc.z = fmaf(f1.x, v, acc.z);
    acc.w = fmaf(f1.y, v, acc.w);
}

// ---- main fused kernel, fp16 table path ----
__global__ __launch_bounds__(256) void nnue_fwd_fp16(
    const int*    __restrict__ wfeat,
    const float*  __restrict__ wval,
    const int*    __restrict__ bfeat,
    const float*  __restrict__ bval,
    const uint2*  __restrict__ ftw16,  // [40960][64] x 4 halfs
    const float4* __restrict__ ftb,    // [64] float4
    const float*  __restrict__ fc1w,   // [512][32]
    const float*  __restrict__ fc1b,
    const float*  __restrict__ fc2w,   // [32][32]
    const float*  __restrict__ fc2b,
    const float*  __restrict__ fc3w,   // [32]
    const float*  __restrict__ fc3b,
    float*        __restrict__ out)
{
    __shared__ float x[4][2 * HIDDEN];
    __shared__ float p1[4][2][32];
    __shared__ float h1[4][32];
    __shared__ float h2[4][32];

    const int tid   = threadIdx.x;
    const int w     = tid >> 6;
    const int lane  = tid & 63;
    const int board = (blockIdx.x << 2) + w;

    // one coalesced load of this board's 64 (idx,val) pairs; shfl-broadcast
    const int   myidx = (lane < 32) ? wfeat[board * NNZPB + lane]
                                    : bfeat[board * NNZPB + (lane - 32)];
    const float myval = (lane < 32) ? wval[board * NNZPB + lane]
                                    : bval[board * NNZPB + (lane - 32)];

    float4 accw = ftb[lane];
    float4 accb = accw;

    #pragma unroll 16
    for (int k = 0; k < NNZPB; ++k) {
        const int   fw = __shfl(myidx, k);
        const float vw = __shfl(myval, k);
        const int   fb = __shfl(myidx, 32 + k);
        const float vb = __shfl(myval, 32 + k);
        const uint2 rw = ftw16[fw * 64 + lane];
        const uint2 rb = ftw16[fb * 64 + lane];
        fma4_fp16(rw, vw, accw);
        fma4_fp16(rb, vb, accb);
    }

    {
        float4 c;
        c.x = crelu1(accw.x); c.y = crelu1(accw.y);
        c.z = crelu1(accw.z); c.w = crelu1(accw.w);
        reinterpret_cast<float4*>(x[w])[lane] = c;
        c.x = crelu1(accb.x); c.y = crelu1(accb.y);
        c.z = crelu1(accb.z); c.w = crelu1(accb.w);
        reinterpret_cast<float4*>(x[w])[64 + lane] = c;
    }

    __syncthreads();

    // fc1: lane -> (o = lane&31, half = lane>>5), 256-elem dot each
    {
        const int o = lane & 31;
        const int h = lane >> 5;
        const float* xr = &x[w][h * HIDDEN];
        const float* wr = fc1w + (h * HIDDEN) * 32 + o;
        float s = 0.0f;
        #pragma unroll 8
        for (int i = 0; i < HIDDEN; ++i)
            s = fmaf(xr[i], wr[i * 32], s);
        p1[w][h][o] = s;
    }
    __syncthreads();

    if (lane < 32) {
        const float v = p1[w][0][lane] + p1[w][1][lane] + fc1b[lane];
        h1[w][lane] = crelu1(v);
    }
    __syncthreads();

    if (lane < 32) {
        float s = fc2b[lane];
        #pragma unroll
        for (int i = 0; i < 32; ++i)
            s = fmaf(h1[w][i], fc2w[i * 32 + lane], s);
        h2[w][lane] = crelu1(s);
    }
    __syncthreads();

    if (lane == 0) {
        float s = fc3b[0];
        #pragma unroll
        for (int i = 0; i < 32; ++i)
            s = fmaf(h2[w][i], fc3w[i], s);
        out[board] = s;
    }
}

// ---- f32 fallback (identical to R1) in case ws_size < 21 MB ----
__global__ __launch_bounds__(256) void nnue_fwd_f32(
    const int*    __restrict__ wfeat,
    const float*  __restrict__ wval,
    const int*    __restrict__ bfeat,
    const float*  __restrict__ bval,
    const float4* __restrict__ ftw,
    const float4* __restrict__ ftb,
    const float*  __restrict__ fc1w,
    const float*  __restrict__ fc1b,
    const float*  __restrict__ fc2w,
    const float*  __restrict__ fc2b,
    const float*  __restrict__ fc3w,
    const float*  __restrict__ fc3b,
    float*        __restrict__ out)
{
    __shared__ float x[4][2 * HIDDEN];
    __shared__ float p1[4][2][32];
    __shared__ float h1[4][32];
    __shared__ float h2[4][32];

    const int tid   = threadIdx.x;
    const int w     = tid >> 6;
    const int lane  = tid & 63;
    const int board = (blockIdx.x << 2) + w;

    const int   myidx = (lane < 32) ? wfeat[board * NNZPB + lane]
                                    : bfeat[board * NNZPB + (lane - 32)];
    const float myval = (lane < 32) ? wval[board * NNZPB + lane]
                                    : bval[board * NNZPB + (lane - 32)];

    float4 accw = ftb[lane];
    float4 accb = accw;

    #pragma unroll 8
    for (int k = 0; k < NNZPB; ++k) {
        const int   fw = __shfl(myidx, k);
        const float vw = __shfl(myval, k);
        const int   fb = __shfl(myidx, 32 + k);
        const float vb = __shfl(myval, 32 + k);
        const float4 rw = ftw[fw * 64 + lane];
        const float4 rb = ftw[fb * 64 + lane];
        accw.x = fmaf(rw.x, vw, accw.x); accw.y = fmaf(rw.y, vw, accw.y);
        accw.z = fmaf(rw.z, vw, accw.z); accw.w = fmaf(rw.w, vw, accw.w);
        accb.x = fmaf(rb.x, vb, accb.x); accb.y = fmaf(rb.y, vb, accb.y);
        accb.z = fmaf(rb.z, vb, accb.z); accb.w = fmaf(rb.w, vb, accb.w);
    }

    {
        float4 c;
        c.x = crelu1(accw.x); c.y = crelu1(accw.y);
        c.z = crelu1(accw.z); c.w = crelu1(accw.w);
        reinterpret_cast<float4*>(x[w])[lane] = c;
        c.x = crelu1(accb.x); c.y = crelu1(accb.y);
        c.z = crelu1(accb.z); c.w = crelu1(accb.w);
        reinterpret_cast<float4*>(x[w])[64 + lane] = c;
    }

    __syncthreads();

    {
        const int o = lane & 31;
        const int h = lane >> 5;
        const float* xr = &x[w][h * HIDDEN];
        const float* wr = fc1w + (h * HIDDEN) * 32 + o;
        float s = 0.0f;
        #pragma unroll 8
        for (int i = 0; i < HIDDEN; ++i)
            s = fmaf(xr[i], wr[i * 32], s);
        p1[w][h][o] = s;
    }
    __syncthreads();

    if (lane < 32) {
        const float v = p1[w][0][lane] + p1[w][1][lane] + fc1b[lane];
        h1[w][lane] = crelu1(v);
    }
    __syncthreads();

    if (lane < 32) {
        float s = fc2b[lane];
        #pragma unroll
        for (int i = 0; i < 32; ++i)
            s = fmaf(h1[w][i], fc2w[i * 32 + lane], s);
        h2[w][lane] = crelu1(s);
    }
    __syncthreads();

    if (lane == 0) {
        float s = fc3b[0];
        #pragma unroll
        for (int i = 0; i < 32; ++i)
            s = fmaf(h2[w][i], fc3w[i], s);
        out[board] = s;
    }
}

extern "C" void kernel_launch(void* const* d_in, const int* in_sizes, int n_in,
                              void* d_out, int out_size, void* d_ws, size_t ws_size,
                              hipStream_t stream) {
    const int*   w_indices = (const int*)  d_in[0];
    const float* w_values  = (const float*)d_in[1];
    const int*   b_indices = (const int*)  d_in[2];
    const float* b_values  = (const float*)d_in[3];
    const float* ft_w      = (const float*)d_in[4];
    const float* ft_b      = (const float*)d_in[5];
    const float* fc1_w     = (const float*)d_in[6];
    const float* fc1_b     = (const float*)d_in[7];
    const float* fc2_w     = (const float*)d_in[8];
    const float* fc2_b     = (const float*)d_in[9];
    const float* fc3_w     = (const float*)d_in[10];
    const float* fc3_b     = (const float*)d_in[11];
    float* out = (float*)d_out;

    const int* wfeat = w_indices + NNZ;
    const int* bfeat = b_indices + NNZ;

    if (ws_size >= FTW16_BYTES) {
        uint2* ftw16 = (uint2*)d_ws;
        const int n4 = FEATSZ * HIDDEN / 4;   // 2,621,440 float4s
        convert_ftw<<<2048, 256, 0, stream>>>((const float4*)ft_w, ftw16, n4);
        nnue_fwd_fp16<<<BATCH / 4, 256, 0, stream>>>(
            wfeat, w_values, bfeat, b_values,
            ftw16, (const float4*)ft_b,
            fc1_w, fc1_b, fc2_w, fc2_b, fc3_w, fc3_b, out);
    } else {
        nnue_fwd_f32<<<BATCH / 4, 256, 0, stream>>>(
            wfeat, w_values, bfeat, b_values,
            (const float4*)ft_w, (const float4*)ft_b,
            fc1_w, fc1_b, fc2_w, fc2_b, fc3_w, fc3_b, out);
    }
}

// Round 3
// 89.251 us; speedup vs baseline: 1.6105x; 1.1252x over previous
//
#include <hip/hip_runtime.h>
#include <hip/hip_fp16.h>

// NNUE forward. R3: wave-uniform scalar index path (s_load indices/values into
// SGPRs, SALU address math, saddr-form gathers) replacing R2's 128 ds_bpermute
// per wave. fp16 table (f32 accumulate via v_fma_mix) kept from R2.
// fc1 LDS reads vectorized to float4.

constexpr int BATCH   = 16384;
constexpr int NNZPB   = 32;
constexpr int NNZ     = BATCH * NNZPB;
constexpr int HIDDEN  = 256;
constexpr int FEATSZ  = 64 * 64 * 10;                       // 40960
constexpr size_t FTW16_BYTES = (size_t)FEATSZ * HIDDEN * 2; // 20,971,520

__device__ __forceinline__ float crelu1(float v) {
    return fminf(fmaxf(v, 0.0f), 1.0f);
}

// ---- one-pass f32 -> fp16 table conversion (runs every launch; ~10us) ----
__global__ __launch_bounds__(256) void convert_ftw(
    const float4* __restrict__ src,
    uint2*        __restrict__ dst,
    int n4)
{
    int i = blockIdx.x * 256 + threadIdx.x;
    const int stride = gridDim.x * 256;
    for (; i < n4; i += stride) {
        const float4 v = src[i];
        const __half2 lo = __floats2half2_rn(v.x, v.y);
        const __half2 hi = __floats2half2_rn(v.z, v.w);
        uint2 o;
        o.x = *reinterpret_cast<const unsigned*>(&lo);
        o.y = *reinterpret_cast<const unsigned*>(&hi);
        dst[i] = o;
    }
}

// half2x2 * scalar f32, f32 accumulate; folds to v_fma_mix_f32 on gfx9+
__device__ __forceinline__ void fma4_fp16(const uint2 r, float v, float4& acc) {
    const __half2 h0 = *reinterpret_cast<const __half2*>(&r.x);
    const __half2 h1 = *reinterpret_cast<const __half2*>(&r.y);
    const float2 f0 = __half22float2(h0);
    const float2 f1 = __half22float2(h1);
    acc.x = fmaf(f0.x, v, acc.x);
    acc.y = fmaf(f0.y, v, acc.y);
    acc.z = fmaf(f1.x, v, acc.z);
    acc.w = fmaf(f1.y, v, acc.w);
}

__global__ __launch_bounds__(256) void nnue_fwd_fp16(
    const int*    __restrict__ wfeat,
    const float*  __restrict__ wval,
    const int*    __restrict__ bfeat,
    const float*  __restrict__ bval,
    const uint2*  __restrict__ ftw16,  // [40960][64] x 4 halfs
    const float4* __restrict__ ftb,    // [64] float4
    const float*  __restrict__ fc1w,   // [512][32]
    const float*  __restrict__ fc1b,
    const float*  __restrict__ fc2w,   // [32][32]
    const float*  __restrict__ fc2b,
    const float*  __restrict__ fc3w,   // [32]
    const float*  __restrict__ fc3b,
    float*        __restrict__ out)
{
    __shared__ float x[4][2 * HIDDEN];
    __shared__ float p1[4][2][32];
    __shared__ float h1[4][32];
    __shared__ float h2[4][32];

    const int tid  = threadIdx.x;
    const int w    = tid >> 6;
    const int lane = tid & 63;
    // wave-uniform board index, forced into an SGPR so the index/value loads
    // below become scalar (s_load) and address math lands on the SALU pipe
    const int board = __builtin_amdgcn_readfirstlane((int)(blockIdx.x << 2) + w);

    const int*   wip = wfeat + board * NNZPB;
    const float* wvp = wval  + board * NNZPB;
    const int*   bip = bfeat + board * NNZPB;
    const float* bvp = bval  + board * NNZPB;

    float4 accw = ftb[lane];
    float4 accb = accw;

    #pragma unroll
    for (int k = 0; k < NNZPB; ++k) {
        const int   fw = wip[k];   // uniform -> s_load
        const float vw = wvp[k];
        const int   fb = bip[k];
        const float vb = bvp[k];
        const uint2 rw = ftw16[fw * 64 + lane];  // saddr + lane*8
        const uint2 rb = ftw16[fb * 64 + lane];
        fma4_fp16(rw, vw, accw);
        fma4_fp16(rb, vb, accb);
    }

    {
        float4 c;
        c.x = crelu1(accw.x); c.y = crelu1(accw.y);
        c.z = crelu1(accw.z); c.w = crelu1(accw.w);
        reinterpret_cast<float4*>(x[w])[lane] = c;
        c.x = crelu1(accb.x); c.y = crelu1(accb.y);
        c.z = crelu1(accb.z); c.w = crelu1(accb.w);
        reinterpret_cast<float4*>(x[w])[64 + lane] = c;
    }

    __syncthreads();

    // fc1: lane -> (o = lane&31, half = lane>>5); 256-elem dot each.
    // x reads via ds_read_b128 (broadcast within each half-wave).
    {
        const int o = lane & 31;
        const int h = lane >> 5;
        const float4* xr = reinterpret_cast<const float4*>(&x[w][h * HIDDEN]);
        const float*  wr = fc1w + (h * HIDDEN) * 32 + o;
        float s = 0.0f;
        #pragma unroll 16
        for (int i4 = 0; i4 < HIDDEN / 4; ++i4) {
            const float4 xv = xr[i4];
            s = fmaf(xv.x, wr[(i4 * 4 + 0) * 32], s);
            s = fmaf(xv.y, wr[(i4 * 4 + 1) * 32], s);
            s = fmaf(xv.z, wr[(i4 * 4 + 2) * 32], s);
            s = fmaf(xv.w, wr[(i4 * 4 + 3) * 32], s);
        }
        p1[w][h][o] = s;
    }
    __syncthreads();

    if (lane < 32) {
        const float v = p1[w][0][lane] + p1[w][1][lane] + fc1b[lane];
        h1[w][lane] = crelu1(v);
    }
    __syncthreads();

    if (lane < 32) {
        float s = fc2b[lane];
        #pragma unroll
        for (int i = 0; i < 32; ++i)
            s = fmaf(h1[w][i], fc2w[i * 32 + lane], s);
        h2[w][lane] = crelu1(s);
    }
    __syncthreads();

    if (lane == 0) {
        float s = fc3b[0];
        #pragma unroll
        for (int i = 0; i < 32; ++i)
            s = fmaf(h2[w][i], fc3w[i], s);
        out[board] = s;
    }
}

// ---- f32 fallback in case ws_size < 21 MB (same scalar-index structure) ----
__global__ __launch_bounds__(256) void nnue_fwd_f32(
    const int*    __restrict__ wfeat,
    const float*  __restrict__ wval,
    const int*    __restrict__ bfeat,
    const float*  __restrict__ bval,
    const float4* __restrict__ ftw,
    const float4* __restrict__ ftb,
    const float*  __restrict__ fc1w,
    const float*  __restrict__ fc1b,
    const float*  __restrict__ fc2w,
    const float*  __restrict__ fc2b,
    const float*  __restrict__ fc3w,
    const float*  __restrict__ fc3b,
    float*        __restrict__ out)
{
    __shared__ float x[4][2 * HIDDEN];
    __shared__ float p1[4][2][32];
    __shared__ float h1[4][32];
    __shared__ float h2[4][32];

    const int tid  = threadIdx.x;
    const int w    = tid >> 6;
    const int lane = tid & 63;
    const int board = __builtin_amdgcn_readfirstlane((int)(blockIdx.x << 2) + w);

    const int*   wip = wfeat + board * NNZPB;
    const float* wvp = wval  + board * NNZPB;
    const int*   bip = bfeat + board * NNZPB;
    const float* bvp = bval  + board * NNZPB;

    float4 accw = ftb[lane];
    float4 accb = accw;

    #pragma unroll
    for (int k = 0; k < NNZPB; ++k) {
        const int   fw = wip[k];
        const float vw = wvp[k];
        const int   fb = bip[k];
        const float vb = bvp[k];
        const float4 rw = ftw[fw * 64 + lane];
        const float4 rb = ftw[fb * 64 + lane];
        accw.x = fmaf(rw.x, vw, accw.x); accw.y = fmaf(rw.y, vw, accw.y);
        accw.z = fmaf(rw.z, vw, accw.z); accw.w = fmaf(rw.w, vw, accw.w);
        accb.x = fmaf(rb.x, vb, accb.x); accb.y = fmaf(rb.y, vb, accb.y);
        accb.z = fmaf(rb.z, vb, accb.z); accb.w = fmaf(rb.w, vb, accb.w);
    }

    {
        float4 c;
        c.x = crelu1(accw.x); c.y = crelu1(accw.y);
        c.z = crelu1(accw.z); c.w = crelu1(accw.w);
        reinterpret_cast<float4*>(x[w])[lane] = c;
        c.x = crelu1(accb.x); c.y = crelu1(accb.y);
        c.z = crelu1(accb.z); c.w = crelu1(accb.w);
        reinterpret_cast<float4*>(x[w])[64 + lane] = c;
    }

    __syncthreads();

    {
        const int o = lane & 31;
        const int h = lane >> 5;
        const float4* xr = reinterpret_cast<const float4*>(&x[w][h * HIDDEN]);
        const float*  wr = fc1w + (h * HIDDEN) * 32 + o;
        float s = 0.0f;
        #pragma unroll 16
        for (int i4 = 0; i4 < HIDDEN / 4; ++i4) {
            const float4 xv = xr[i4];
            s = fmaf(xv.x, wr[(i4 * 4 + 0) * 32], s);
            s = fmaf(xv.y, wr[(i4 * 4 + 1) * 32], s);
            s = fmaf(xv.z, wr[(i4 * 4 + 2) * 32], s);
            s = fmaf(xv.w, wr[(i4 * 4 + 3) * 32], s);
        }
        p1[w][h][o] = s;
    }
    __syncthreads();

    if (lane < 32) {
        const float v = p1[w][0][lane] + p1[w][1][lane] + fc1b[lane];
        h1[w][lane] = crelu1(v);
    }
    __syncthreads();

    if (lane < 32) {
        float s = fc2b[lane];
        #pragma unroll
        for (int i = 0; i < 32; ++i)
            s = fmaf(h1[w][i], fc2w[i * 32 + lane], s);
        h2[w][lane] = crelu1(s);
    }
    __syncthreads();

    if (lane == 0) {
        float s = fc3b[0];
        #pragma unroll
        for (int i = 0; i < 32; ++i)
            s = fmaf(h2[w][i], fc3w[i], s);
        out[board] = s;
    }
}

extern "C" void kernel_launch(void* const* d_in, const int* in_sizes, int n_in,
                              void* d_out, int out_size, void* d_ws, size_t ws_size,
                              hipStream_t stream) {
    const int*   w_indices = (const int*)  d_in[0];
    const float* w_values  = (const float*)d_in[1];
    const int*   b_indices = (const int*)  d_in[2];
    const float* b_values  = (const float*)d_in[3];
    const float* ft_w      = (const float*)d_in[4];
    const float* ft_b      = (const float*)d_in[5];
    const float* fc1_w     = (const float*)d_in[6];
    const float* fc1_b     = (const float*)d_in[7];
    const float* fc2_w     = (const float*)d_in[8];
    const float* fc2_b     = (const float*)d_in[9];
    const float* fc3_w     = (const float*)d_in[10];
    const float* fc3_b     = (const float*)d_in[11];
    float* out = (float*)d_out;

    const int* wfeat = w_indices + NNZ;
    const int* bfeat = b_indices + NNZ;

    if (ws_size >= FTW16_BYTES) {
        uint2* ftw16 = (uint2*)d_ws;
        const int n4 = FEATSZ * HIDDEN / 4;
        convert_ftw<<<2048, 256, 0, stream>>>((const float4*)ft_w, ftw16, n4);
        nnue_fwd_fp16<<<BATCH / 4, 256, 0, stream>>>(
            wfeat, w_values, bfeat, b_values,
            ftw16, (const float4*)ft_b,
            fc1_w, fc1_b, fc2_w, fc2_b, fc3_w, fc3_b, out);
    } else {
        nnue_fwd_f32<<<BATCH / 4, 256, 0, stream>>>(
            wfeat, w_values, bfeat, b_values,
            (const float4*)ft_w, (const float4*)ft_b,
            fc1_w, fc1_b, fc2_w, fc2_b, fc3_w, fc3_b, out);
    }
}